// Round 5
// baseline (160.682 us; speedup 1.0000x reference)
//
#include <hip/hip_runtime.h>
#include <math.h>

// TQUnitaryBuilder: 9-wire, 4-layer circuit -> U (512x512 real) per sample,
// fused with closed-form expm of the rank-2 skew matrix and the final matmul.
//
// Round-5 = round-4 resubmit (infra failure) with launch-bounds fix.
// 2-exchange layout: each column spread over 16 lanes x 32 els (4 cols/wave).
// 5 local bits -> each layer is
//   round A (wires 4..8 on local bits x4..x0) -> exchange E1 ->
//   round B (wires 0..3 on bits x8..x5) + diag -> exchange E2 (ring folded)
// i.e. 2 LDS round-trips per layer instead of 3 (16 KB vs 24 KB per col-layer,
// the binding LDS-pipe cost in rounds 0-2's 71-us plateau).
// Layouts: round A lane mu holds x = mu*32 + i; round B lane mu holds els
// i' with x = (i'>>1)<<5 | mu<<1 | (i'&1) (bit x0 stays local in both).
// Swizzle pm2(y) = y ^ (((y>>5)&15)<<1) (GF2-linear; keeps b128 pairs in
// order, even bank spread; ring perm F folds into lane base ^ consts).
// Diag = DB[x8..x5,x0] (SGPR dual, 32 entries) * DA[x4..x1] (per-lane, 16).
// Blocks: 128 thr = 2 waves = 8 cols, 32 KB LDS (5 blocks/CU); epilogue is
// the round-2 exact-WRITE form (32-B granules, blockIdx = cb*64+s).
// __launch_bounds__(128,2): 4 waves/EU was unachievable under 32KB LDS and
// capped VGPR at 128 (layer-1 t-pyramid + amp[32] would spill).
//
// ws layout (floats), stride 2560 per sample s:
//   [0..143]    layer-1 dual gates: 9 x 4 entries x (gr,gi,-gi,gr)
//   [144..146]  expm scalars: cos(th), alpha, beta
//   [160+l*256 ..] per layer l (sim uses l=1..3):
//     +0..35    rot coeffs: 9 wires x {c,-s,s,c}
//     +64..191  DB dual: 32 x {Br,Bi,-Bi,Br}   (wires 0,1,2,3,8)
//     +192..223 DA: 16 x {Ar,Ai}               (wires 4,5,6,7)
//   [1184..1255] v[72] (0.01*params, v[0]=0)
//   [1280..1791] w[512]   = alpha*u0 - beta*Uv
//   [1792..2303] c0[512]  = cos(th)*u0 - alpha*Uv

#define PSTRIDE 2560
#define GD_OFF  0
#define SC_OFF  144
#define L_OFF(l) (160 + (l)*256)
#define V_OFF   1184
#define W_OFF   1280
#define C0_OFF  1792

__device__ __forceinline__ float2 cmul(float2 a, float2 b){
  return make_float2(fmaf(a.x, b.x, -a.y*b.y), fmaf(a.x, b.y, a.y*b.x));
}

// ---- packed fp32 helpers (v_pk_fma_f32 / v_pk_mul_f32, full-rate) ----
__device__ __forceinline__ float2 pk_fma_s_lo(float2 s2, float2 b, float2 c){
  float2 d;  // d = s2.x * b + c   (s2 SGPR)
  asm("v_pk_fma_f32 %0, %1, %2, %3 op_sel:[0,0,0] op_sel_hi:[0,1,1]"
      : "=v"(d) : "s"(s2), "v"(b), "v"(c));
  return d;
}
__device__ __forceinline__ float2 pk_mul_s_hi(float2 s2, float2 b){
  float2 d;  // d = s2.y * b
  asm("v_pk_mul_f32 %0, %1, %2 op_sel:[1,0] op_sel_hi:[1,1]"
      : "=v"(d) : "s"(s2), "v"(b));
  return d;
}
__device__ __forceinline__ float2 pk_fma_vs_lo(float2 a, float2 b, float2 c){
  float2 d;  // d = a.x * b + c   (a VGPR broadcast, b SGPR)
  asm("v_pk_fma_f32 %0, %1, %2, %3 op_sel:[0,0,0] op_sel_hi:[0,1,1]"
      : "=v"(d) : "v"(a), "s"(b), "v"(c));
  return d;
}
__device__ __forceinline__ float2 pk_mul_vs_hi(float2 a, float2 b){
  float2 d;  // d = a.y * b
  asm("v_pk_mul_f32 %0, %1, %2 op_sel:[1,0] op_sel_hi:[1,1]"
      : "=v"(d) : "v"(a), "s"(b));
  return d;
}
__device__ __forceinline__ float2 pk_fma_vv_lo(float2 a, float2 b, float2 c){
  float2 d;  // d = a.x * b + c
  asm("v_pk_fma_f32 %0, %1, %2, %3 op_sel:[0,0,0] op_sel_hi:[0,1,1]"
      : "=v"(d) : "v"(a), "v"(b), "v"(c));
  return d;
}
__device__ __forceinline__ float2 pk_mul_vv_hi(float2 a, float2 b){
  float2 d;  // d = a.y * b
  asm("v_pk_mul_f32 %0, %1, %2 op_sel:[1,0] op_sel_hi:[1,1]"
      : "=v"(d) : "v"(a), "v"(b));
  return d;
}
__device__ __forceinline__ float2 pk_swapneg(float2 c, float2 n){
  float2 d;  // d = (-c.y, c.x)   with n = (-1, 1)
  asm("v_pk_mul_f32 %0, %1, %2 op_sel:[1,0] op_sel_hi:[0,1]"
      : "=v"(d) : "v"(c), "v"(n));
  return d;
}

__device__ __forceinline__ int Fperm(int x){       // forward ring permutation
  int S = x ^ (x >> 1); S ^= S >> 2; S ^= S >> 4; S ^= S >> 8;
  return (S & 0xFF) | ((((x >> 8) ^ S) & 1) << 8);
}
__device__ __forceinline__ int physmap(int x){ return x ^ ((x >> 4) & 15); }
__device__ __forceinline__ int pm2(int y){ return y ^ (((y >> 5) & 15) << 1); }

// ---- float2 path (prep phase-2 column sims; OLD 8-el layout, unchanged) ----
template<int STRIDE>
__device__ __forceinline__ void apply_rot2(float2 amp[8], const float* rp){
  const float2 R0 = ((const float2*)rp)[0];            // (c, -s)
  const float2 R1 = ((const float2*)rp)[1];            // (s,  c)
  #pragma unroll
  for (int b = 0; b < 8; ++b){
    if (b & STRIDE) continue;
    const float2 u = amp[b], v = amp[b + STRIDE];
    amp[b]          = pk_fma_vv_lo(R0, u, pk_mul_vv_hi(R0, v));
    amp[b + STRIDE] = pk_fma_vv_lo(R1, u, pk_mul_vv_hi(R1, v));
  }
}

__device__ __forceinline__ void run_layer2(float2* __restrict__ S,
    const float* __restrict__ lb, const int lane,
    const int base1, const int base2, const int base3, const int baseF,
    const float2 NEG1P1){
  float2 amp[8];
  #pragma unroll
  for (int j = 0; j < 8; ++j) amp[j] = S[base1 ^ j];
  apply_rot2<4>(amp, lb + 6*4);
  apply_rot2<2>(amp, lb + 7*4);
  apply_rot2<1>(amp, lb + 8*4);
  #pragma unroll
  for (int j = 0; j < 8; ++j) S[base1 ^ j] = amp[j];
  #pragma unroll
  for (int j = 0; j < 8; ++j) amp[j] = S[base2 ^ ((j << 3) ^ (j >> 1))];
  apply_rot2<4>(amp, lb + 3*4);
  apply_rot2<2>(amp, lb + 4*4);
  apply_rot2<1>(amp, lb + 5*4);
  #pragma unroll
  for (int j = 0; j < 8; ++j) S[base2 ^ ((j << 3) ^ (j >> 1))] = amp[j];
  #pragma unroll
  for (int j = 0; j < 8; ++j) amp[j] = S[base3 ^ ((j << 6) ^ ((4*j) & 15))];
  apply_rot2<4>(amp, lb + 0*4);
  apply_rot2<2>(amp, lb + 1*4);
  apply_rot2<1>(amp, lb + 2*4);
  {
    const float2 A  = *(const float2*)(lb + 128 + lane*2);
    const float2 A2 = pk_swapneg(A, NEG1P1);             // (-Ai, Ar)
    #pragma unroll
    for (int j = 0; j < 8; ++j)
      amp[j] = pk_fma_vv_lo(amp[j], A, pk_mul_vv_hi(amp[j], A2));
    #pragma unroll
    for (int j = 0; j < 8; ++j){
      const float2 P = *(const float2*)(lb + 64 + j*4);
      const float2 Q = *(const float2*)(lb + 64 + j*4 + 2);
      amp[j] = pk_fma_vv_lo(amp[j], P, pk_mul_vv_hi(amp[j], Q));
    }
  }
  #pragma unroll
  for (int j = 0; j < 8; ++j) S[baseF ^ physmap(Fperm(j << 6))] = amp[j];
}

// ---- 32-el rotation on the new layout (coeffs wave-uniform SGPR) ----
template<int STRIDE>
__device__ __forceinline__ void rot32(float2 amp[32], const float* rp){
  const float2 R0 = ((const float2*)rp)[0];            // (c, -s)
  const float2 R1 = ((const float2*)rp)[1];            // (s,  c)
  #pragma unroll
  for (int b = 0; b < 32; ++b){
    if (b & STRIDE) continue;
    const float2 u = amp[b], v = amp[b + STRIDE];
    amp[b]          = pk_fma_s_lo(R0, u, pk_mul_s_hi(R0, v));
    amp[b + STRIDE] = pk_fma_s_lo(R1, u, pk_mul_s_hi(R1, v));
  }
}

// ---------------- kernel 1: MLP + tables + u0/Uv column sims ----------------
__global__ __launch_bounds__(576)
void prep_kernel(const float* __restrict__ t,  const float* __restrict__ w1,
                 const float* __restrict__ b1, const float* __restrict__ w2,
                 const float* __restrict__ b2, float* __restrict__ prep){
  __shared__ float sh[512];
  __shared__ float part[8][72];
  __shared__ float spar[72];
  __shared__ float tl[4][256];               // LDS tables (OLD form, phase-2)
  __shared__ float ssc[3];
  __shared__ __align__(16) float2 vst[2][512];
  const int s = blockIdx.x;
  const float ts = t[s];
  for (int k = threadIdx.x; k < 512; k += 576){
    const float z = fmaf(ts, w1[k], b1[k]);
    sh[k] = z / (1.f + expf(-z));            // silu
  }
  __syncthreads();
  {
    const int p = threadIdx.x % 72, c = threadIdx.x / 72;   // c in 0..7
    float acc = 0.f;
    const int k0 = c*64;
    for (int k = k0; k < k0 + 64; ++k) acc = fmaf(sh[k], w2[k*72 + p], acc);
    part[c][p] = acc;
  }
  __syncthreads();
  if (threadIdx.x < 72){
    const int p = threadIdx.x;
    float acc = b2[p];
    #pragma unroll
    for (int c = 0; c < 8; ++c) acc += part[c][p];
    spar[p] = acc;
  }
  __syncthreads();
  float* pb = prep + (size_t)s*PSTRIDE;
  const int tid = threadIdx.x;
  if (tid < 256){                            // OLD A[64] l=0..3 -> tl ONLY
    const int l = tid >> 6, m = tid & 63;
    float2 acc = make_float2(1.f, 0.f);
    #pragma unroll
    for (int w = 3; w < 9; ++w){
      const float thz = spar[2*(9*l + w) + 1];
      float zi, zr; sincosf(0.5f*thz, &zi, &zr);
      const int bit = (m >> (8 - w)) & 1;
      acc = cmul(acc, make_float2(zr, bit ? zi : -zi));
    }
    tl[l][128 + 2*m]     = acc.x;
    tl[l][128 + 2*m + 1] = acc.y;
  } else if (tid < 288){                     // OLD B dual l=0..3 -> tl ONLY
    const int q = tid - 256, l = q >> 3, j = q & 7;
    float2 acc = make_float2(1.f, 0.f);
    #pragma unroll
    for (int w = 0; w < 3; ++w){
      const float thz = spar[2*(9*l + w) + 1];
      float zi, zr; sincosf(0.5f*thz, &zi, &zr);
      const int bit = (j >> (2 - w)) & 1;
      acc = cmul(acc, make_float2(zr, bit ? zi : -zi));
    }
    float* o2 = &tl[l][64 + j*4];
    o2[0] = acc.x; o2[1] = acc.y; o2[2] = -acc.y; o2[3] = acc.x;
  } else if (tid < 324){                     // rot coeffs l=0..3 -> pb + tl
    const int q = tid - 288, l = q / 9, w = q - l*9;
    const float thy = spar[2*(9*l + w)];
    float sy, cy; sincosf(0.5f*thy, &sy, &cy);
    float* o = pb + L_OFF(l) + w*4;
    o[0] = cy; o[1] = -sy; o[2] = sy; o[3] = cy;
    float* o2 = &tl[l][w*4];
    o2[0] = cy; o2[1] = -sy; o2[2] = sy; o2[3] = cy;
  } else if (tid < 333){                     // layer-1 dual gates
    const int w = tid - 324;
    const float thy = spar[2*w], thz = spar[2*w + 1];
    float sy, cy, zi, zr;
    sincosf(0.5f*thy, &sy, &cy);
    sincosf(0.5f*thz, &zi, &zr);             // e = (zr, zi)
    const float gr[4] = { zr*cy, -zr*sy, zr*sy, zr*cy };
    const float gi[4] = { -zi*cy, zi*sy, zi*sy, zi*cy };
    float* o = pb + GD_OFF + w*16;
    #pragma unroll
    for (int e = 0; e < 4; ++e){
      o[e*4+0] = gr[e]; o[e*4+1] = gi[e]; o[e*4+2] = -gi[e]; o[e*4+3] = gr[e];
    }
  } else if (tid < 405){                     // v[72]
    const int j = tid - 333;
    pb[V_OFF + j] = (j == 0) ? 0.f : 0.01f*spar[j];
  } else if (tid == 405){                    // expm scalars
    float th2 = 0.f;
    for (int j = 1; j < 72; ++j){ const float v = 0.01f*spar[j]; th2 = fmaf(v, v, th2); }
    const float th = sqrtf(th2);
    float alpha, beta;
    if (th > 1e-6f){
      alpha = sinf(th)/th;
      const float s2 = sinf(0.5f*th);
      beta = 2.f*s2*s2/th2;
    } else { alpha = 1.f - th2/6.f; beta = 0.5f; }
    pb[SC_OFF+0] = cosf(th);
    pb[SC_OFF+1] = alpha;
    pb[SC_OFF+2] = beta;
    ssc[0] = cosf(th); ssc[1] = alpha; ssc[2] = beta;
  } else if (tid < 502){                     // NEW DB dual[32], l=1..3
    const int q = tid - 406, l = (q >> 5) + 1, i = q & 31;
    float2 acc = make_float2(1.f, 0.f);
    float zi, zr;
    sincosf(0.5f*spar[2*(9*l + 0) + 1], &zi, &zr);   // wire 0 <- bit i>>4
    acc = cmul(acc, make_float2(zr, ((i >> 4) & 1) ? zi : -zi));
    sincosf(0.5f*spar[2*(9*l + 1) + 1], &zi, &zr);   // wire 1 <- (i>>3)&1
    acc = cmul(acc, make_float2(zr, ((i >> 3) & 1) ? zi : -zi));
    sincosf(0.5f*spar[2*(9*l + 2) + 1], &zi, &zr);   // wire 2 <- (i>>2)&1
    acc = cmul(acc, make_float2(zr, ((i >> 2) & 1) ? zi : -zi));
    sincosf(0.5f*spar[2*(9*l + 3) + 1], &zi, &zr);   // wire 3 <- (i>>1)&1
    acc = cmul(acc, make_float2(zr, ((i >> 1) & 1) ? zi : -zi));
    sincosf(0.5f*spar[2*(9*l + 8) + 1], &zi, &zr);   // wire 8 <- i&1
    acc = cmul(acc, make_float2(zr, (i & 1) ? zi : -zi));
    float* o = pb + L_OFF(l) + 64 + i*4;
    o[0] = acc.x; o[1] = acc.y; o[2] = -acc.y; o[3] = acc.x;
  } else if (tid < 550){                     // NEW DA[16], l=1..3
    const int q = tid - 502, l = (q >> 4) + 1, m = q & 15;
    float2 acc = make_float2(1.f, 0.f);
    float zi, zr;
    sincosf(0.5f*spar[2*(9*l + 4) + 1], &zi, &zr);   // wire 4 <- m>>3
    acc = cmul(acc, make_float2(zr, ((m >> 3) & 1) ? zi : -zi));
    sincosf(0.5f*spar[2*(9*l + 5) + 1], &zi, &zr);   // wire 5 <- (m>>2)&1
    acc = cmul(acc, make_float2(zr, ((m >> 2) & 1) ? zi : -zi));
    sincosf(0.5f*spar[2*(9*l + 6) + 1], &zi, &zr);   // wire 6 <- (m>>1)&1
    acc = cmul(acc, make_float2(zr, ((m >> 1) & 1) ? zi : -zi));
    sincosf(0.5f*spar[2*(9*l + 7) + 1], &zi, &zr);   // wire 7 <- m&1
    acc = cmul(acc, make_float2(zr, (m & 1) ? zi : -zi));
    pb[L_OFF(l) + 192 + m*2]     = acc.x;
    pb[L_OFF(l) + 192 + m*2 + 1] = acc.y;
  }
  __syncthreads();
  // ---- phase 2: simulate circuit on e0 (wave 0) and on v (wave 1) ----
  if (tid < 128){
    const int wv = tid >> 6, lane = tid & 63;
    float2* const S = vst[wv];
    const float2 NEG1P1 = make_float2(-1.f, 1.f);
    const int base1 = (lane << 3) ^ ((lane >> 1) & 15);
    const int hq = lane >> 3, lq = lane & 7;
    const int base2 = (hq << 6) ^ ((hq << 2) & 15) ^ lq;
    const int base3 = lane ^ (lane >> 4);
    const int baseF = physmap(Fperm(lane));
    #pragma unroll
    for (int j = 0; j < 8; ++j){
      const int x = (lane << 3) + j;
      float re;
      if (wv == 0) re = (x == 0) ? 1.f : 0.f;
      else         re = (x >= 1 && x < 72) ? 0.01f*spar[x] : 0.f;
      S[base1 ^ j] = make_float2(re, 0.f);
    }
    #pragma unroll
    for (int L = 0; L < 4; ++L)
      run_layer2(S, &tl[L][0], lane, base1, base2, base3, baseF, NEG1P1);
  }
  __syncthreads();
  if (tid < 512){                            // w / c0 tables
    const int a  = tid;
    const int pa = a ^ ((a >> 4) & 15);
    const float u0 = vst[0][pa].x;
    const float uv = vst[1][pa].x;
    pb[W_OFF  + a] = fmaf(ssc[1], u0, -ssc[2]*uv);   // alpha*u0 - beta*Uv
    pb[C0_OFF + a] = fmaf(ssc[0], u0, -ssc[1]*uv);   // cth*u0 - alpha*Uv
  }
}

// ---------------- kernel 2: circuit sim -> out = U*expm (fused) ----------------
// Grid: blockIdx = cb*64 + s, cb 0..63 (8 cols/block, same-XCD per sample).
// Block 128 thr = 2 waves; each wave: 4 cols, one per 16-lane group.
__global__ __launch_bounds__(128, 2)
void sim_kernel(const float* __restrict__ prep, float* __restrict__ out){
  __shared__ __align__(16) float2 ST[2][2048];       // 32 KiB
  const int s    = blockIdx.x & 63;
  const int cb   = blockIdx.x >> 6;                  // 0..63
  const int wid  = threadIdx.x >> 6;                 // 0..1
  const int lane = threadIdx.x & 63;
  const int g    = lane >> 4;                        // col group 0..3
  const int mu   = lane & 15;
  const int col  = cb*8 + wid*4 + g;
  const float* gp = prep + (size_t)s*PSTRIDE;
  float2* const S = ST[wid];
  const int Wbase = g*512;
  const int tm    = 2*mu;                            // pm2 xor for own range
  const int rdb   = Wbase + mu*32;                   // own slot range base

  float2 amp[32];
  // ---- layer 1 on basis state |col>: product state over all 9 wires ----
  {
    // base: wires 0..3 (x bits = mu b3..b0), input bits col b8..b5
    float2 base = make_float2(1.f, 0.f);
    #pragma unroll
    for (int w = 0; w < 4; ++w){
      const int xb = (mu  >> (3 - w)) & 1;
      const int ib = (col >> (8 - w)) & 1;
      const float2 gv = *(const float2*)(gp + GD_OFF + w*16 + (xb*2 + ib)*4);
      base = cmul(base, gv);
    }
    // factor tables wires 4..8 (value = first half of dual entry)
    float2 a4[2], a5[2], a6[2], a7[2], a8[2];
    #pragma unroll
    for (int b = 0; b < 2; ++b){
      a4[b] = *(const float2*)(gp + GD_OFF + 4*16 + (b*2 + ((col>>4)&1))*4);
      a5[b] = *(const float2*)(gp + GD_OFF + 5*16 + (b*2 + ((col>>3)&1))*4);
      a6[b] = *(const float2*)(gp + GD_OFF + 6*16 + (b*2 + ((col>>2)&1))*4);
      a7[b] = *(const float2*)(gp + GD_OFF + 7*16 + (b*2 + ((col>>1)&1))*4);
      a8[b] = *(const float2*)(gp + GD_OFF + 8*16 + (b*2 + (col&1))*4);
    }
    float2 t1[2], t2[4], t3[8], t4[16];
    #pragma unroll
    for (int b = 0; b < 2; ++b) t1[b] = cmul(base, a4[b]);
    #pragma unroll
    for (int k = 0; k < 2; ++k)
      #pragma unroll
      for (int b = 0; b < 2; ++b) t2[k*2+b] = cmul(t1[k], a5[b]);
    #pragma unroll
    for (int k = 0; k < 4; ++k)
      #pragma unroll
      for (int b = 0; b < 2; ++b) t3[k*2+b] = cmul(t2[k], a6[b]);
    #pragma unroll
    for (int k = 0; k < 8; ++k)
      #pragma unroll
      for (int b = 0; b < 2; ++b) t4[k*2+b] = cmul(t3[k], a7[b]);
    #pragma unroll
    for (int i = 0; i < 32; ++i) amp[i] = cmul(t4[i>>1], a8[i&1]);
    // init scatter with layer-1 ring folded: el x = mu*32+i -> slot pm2(F(x))
    const int IbB = Wbase + pm2(Fperm(mu << 5));
    #pragma unroll
    for (int i = 0; i < 32; ++i) S[IbB ^ pm2(Fperm(i))] = amp[i];
  }

  const int Fb2 = Wbase + pm2(Fperm(mu << 1));       // E2 per-lane base
  const float2 NEG1P1 = make_float2(-1.f, 1.f);

  #pragma unroll
  for (int L = 1; L <= 3; ++L){
    const float* lb = gp + L_OFF(L);
    // ---- round A read: els x = mu*32 + i (b128 pairs, swizzled in-order) --
    #pragma unroll
    for (int a = 0; a < 16; ++a){
      const float4 v = *(const float4*)&S[rdb + ((2*a) ^ tm)];
      amp[2*a]   = make_float2(v.x, v.y);
      amp[2*a+1] = make_float2(v.z, v.w);
    }
    // round A rotations: wires 4..8 on x bits 4..0
    rot32<16>(amp, lb + 4*4);
    rot32< 8>(amp, lb + 5*4);
    rot32< 4>(amp, lb + 6*4);
    rot32< 2>(amp, lb + 7*4);
    rot32< 1>(amp, lb + 8*4);
    // ---- E1: el i=2a+b -> lane a, i' = 2*mu+b (b128 pairs) ----
    #pragma unroll
    for (int a = 0; a < 16; ++a){
      const int sl = Wbase + a*32 + (tm ^ ((2*a) & 31));
      float4 v; v.x = amp[2*a].x; v.y = amp[2*a].y;
      v.z = amp[2*a+1].x; v.w = amp[2*a+1].y;
      *(float4*)&S[sl] = v;
    }
    // ---- round B read: els i' (same swizzled pattern as A-read) ----
    #pragma unroll
    for (int a = 0; a < 16; ++a){
      const float4 v = *(const float4*)&S[rdb + ((2*a) ^ tm)];
      amp[2*a]   = make_float2(v.x, v.y);
      amp[2*a+1] = make_float2(v.z, v.w);
    }
    // round B rotations: wires 0..3 on i' bits 4..1
    rot32<16>(amp, lb + 0*4);
    rot32< 8>(amp, lb + 1*4);
    rot32< 4>(amp, lb + 2*4);
    rot32< 2>(amp, lb + 3*4);
    // diag: amp *= DA[mu] (lane) then *= DB[i'] (SGPR dual)
    {
      const float2 A  = *(const float2*)(lb + 192 + mu*2);
      const float2 A2 = pk_swapneg(A, NEG1P1);
      #pragma unroll
      for (int i = 0; i < 32; ++i)
        amp[i] = pk_fma_vv_lo(amp[i], A, pk_mul_vv_hi(amp[i], A2));
      #pragma unroll
      for (int i = 0; i < 32; ++i){
        const float2 P = *(const float2*)(lb + 64 + i*4);
        const float2 Q = *(const float2*)(lb + 64 + i*4 + 2);
        amp[i] = pk_fma_vs_lo(amp[i], P, pk_mul_vs_hi(amp[i], Q));
      }
    }
    // ---- E2 scatter with ring folded: x(mu,i') -> slot pm2(F(x)) ----
    #pragma unroll
    for (int i = 0; i < 32; ++i)
      S[Fb2 ^ pm2(Fperm(((i >> 1) << 5) | (i & 1)))] = amp[i];
  }

  __syncthreads();                            // epilogue reads both waves
  // transposed write of Re(state) with fused rank-2 expm correction.
  // State is in round-A layout: el y of col (wv*4+gg) at ST[wv][gg*512+pm2(y)].
  const float* wt  = gp + W_OFF;
  const float* c0t = gp + C0_OFF;
  const float* vt  = gp + V_OFF;
  const int q  = threadIdx.x & 1;             // which float4 (col quad)
  const int a0 = threadIdx.x >> 1;            // 0..63
  #pragma unroll
  for (int rep = 0; rep < 8; ++rep){
    const int r  = a0 + rep*64;
    const int pr = pm2(r);
    float4 vv;
    vv.x = ST[q][0*512 + pr].x;
    vv.y = ST[q][1*512 + pr].x;
    vv.z = ST[q][2*512 + pr].x;
    vv.w = ST[q][3*512 + pr].x;
    if (cb < 9){                              // cols 0..71 get the correction
      const float  wa = wt[r];
      const float4 vj = *(const float4*)(vt + cb*8 + q*4);
      vv.x = fmaf(wa, vj.x, vv.x);
      vv.y = fmaf(wa, vj.y, vv.y);
      vv.z = fmaf(wa, vj.z, vv.z);
      vv.w = fmaf(wa, vj.w, vv.w);
      if ((cb | q) == 0) vv.x = c0t[r];       // column 0 closed form
    }
    *(float4*)&out[(size_t)s*262144 + (size_t)r*512 + cb*8 + q*4] = vv;
  }
}

extern "C" void kernel_launch(void* const* d_in, const int* in_sizes, int n_in,
                              void* d_out, int out_size, void* d_ws, size_t ws_size,
                              hipStream_t stream){
  const float* t  = (const float*)d_in[0];
  const float* w1 = (const float*)d_in[1];
  const float* b1 = (const float*)d_in[2];
  const float* w2 = (const float*)d_in[3];
  const float* b2 = (const float*)d_in[4];
  float* out  = (float*)d_out;
  float* prep = (float*)d_ws;                 // 64*2560 floats = 640 KiB used
  prep_kernel<<<64,   576, 0, stream>>>(t, w1, b1, w2, b2, prep);
  sim_kernel <<<4096, 128, 0, stream>>>(prep, out);
}

// Round 6
// 144.183 us; speedup vs baseline: 1.1144x; 1.1144x over previous
//
#include <hip/hip_runtime.h>
#include <math.h>

// TQUnitaryBuilder: 9-wire, 4-layer circuit -> U (512x512 real) per sample,
// fused with closed-form expm of the rank-2 skew matrix and the final matmul.
//
// Round-6 = round-1 kernel (best verified: 144.86 us total, sim 72.2 us)
// with ONE change: sim_kernel __launch_bounds__(512,8) -> (512,6).
// Rationale: (512,8) capped the allocator at 64 VGPR and it emitted a
// 32-VGPR body — LDS addresses and coefficients get rematerialized every
// round (~2x essential VALU). (512,6) gives an 85-VGPR budget while the
// ~90KB/CU effective-LDS invariant (measured across rounds 1/2/3/5) keeps
// occupancy at ~22 waves/CU either way: single-variable test of the
// "allocator starvation inflates VALU count" theory at constant occupancy.
//
// Uv = U@v = Re(circuit(v)) and u0 = circuit(e0) are single-column sims done
// in prep's phase 2 (2 waves), producing per-sample tables w[512], c0[512];
// sim_kernel's epilogue applies the rank-2 correction to cols 0..71 directly
// (blocks cb<9 only). Layer-1 gates are stored in "dual" form (gr,gi,-gi,gr)
// so complex mul is 2 v_pk ops; the deferred diagonal phase is applied as
// (amp*A[lane])*B[j] (2+2 pk) instead of amp*(A*B[j]) (5 pk).
//
// ws layout (floats), stride 2560 per sample s:
//   [0..143]    layer-1 dual gates: 9 x 4 entries x (gr,gi,-gi,gr)
//   [144..146]  expm scalars: cos(th), alpha=sin/th, beta=(1-cos)/th^2
//   [160+l*256 ..] split blocks for layers l=0..3:
//     +0..35    rot coeffs: 9 wires x {c,-s,s,c}
//     +64..95   B-phase:    8 j x {Br,Bi,-Bi,Br} (P,Q dual form)
//     +128..255 A-phase:    64 m x {Ar,Ai}
//   [1184..1255] v[72] (0.01*params, v[0]=0)
//   [1280..1791] w[512]   = alpha*u0 - beta*Uv
//   [1792..2303] c0[512]  = cos(th)*u0 - alpha*Uv
// Total: 64 * 2560 * 4 B = 640 KiB of d_ws.

#define PSTRIDE 2560
#define GD_OFF  0
#define SC_OFF  144
#define L_OFF(l) (160 + (l)*256)
#define V_OFF   1184
#define W_OFF   1280
#define C0_OFF  1792

__device__ __forceinline__ float2 cmul(float2 a, float2 b){
  return make_float2(fmaf(a.x, b.x, -a.y*b.y), fmaf(a.x, b.y, a.y*b.x));
}

// ---- packed fp32 helpers (v_pk_fma_f32 / v_pk_mul_f32, full-rate) ----
__device__ __forceinline__ float2 pk_fma_s_lo(float2 s2, float2 b, float2 c){
  float2 d;  // d = s2.x * b + c   (s2 SGPR)
  asm("v_pk_fma_f32 %0, %1, %2, %3 op_sel:[0,0,0] op_sel_hi:[0,1,1]"
      : "=v"(d) : "s"(s2), "v"(b), "v"(c));
  return d;
}
__device__ __forceinline__ float2 pk_mul_s_hi(float2 s2, float2 b){
  float2 d;  // d = s2.y * b
  asm("v_pk_mul_f32 %0, %1, %2 op_sel:[1,0] op_sel_hi:[1,1]"
      : "=v"(d) : "s"(s2), "v"(b));
  return d;
}
__device__ __forceinline__ float2 pk_fma_vs_lo(float2 a, float2 b, float2 c){
  float2 d;  // d = a.x * b + c   (a VGPR broadcast, b SGPR)
  asm("v_pk_fma_f32 %0, %1, %2, %3 op_sel:[0,0,0] op_sel_hi:[0,1,1]"
      : "=v"(d) : "v"(a), "s"(b), "v"(c));
  return d;
}
__device__ __forceinline__ float2 pk_mul_vs_hi(float2 a, float2 b){
  float2 d;  // d = a.y * b
  asm("v_pk_mul_f32 %0, %1, %2 op_sel:[1,0] op_sel_hi:[1,1]"
      : "=v"(d) : "v"(a), "s"(b));
  return d;
}
__device__ __forceinline__ float2 pk_fma_vv_lo(float2 a, float2 b, float2 c){
  float2 d;  // d = a.x * b + c
  asm("v_pk_fma_f32 %0, %1, %2, %3 op_sel:[0,0,0] op_sel_hi:[0,1,1]"
      : "=v"(d) : "v"(a), "v"(b), "v"(c));
  return d;
}
__device__ __forceinline__ float2 pk_mul_vv_hi(float2 a, float2 b){
  float2 d;  // d = a.y * b
  asm("v_pk_mul_f32 %0, %1, %2 op_sel:[1,0] op_sel_hi:[1,1]"
      : "=v"(d) : "v"(a), "v"(b));
  return d;
}
__device__ __forceinline__ float2 pk_swapneg(float2 c, float2 n){
  float2 d;  // d = (-c.y, c.x)   with n = (-1, 1)
  asm("v_pk_mul_f32 %0, %1, %2 op_sel:[1,0] op_sel_hi:[0,1]"
      : "=v"(d) : "v"(c), "v"(n));
  return d;
}

__device__ __forceinline__ int Fperm(int x){       // forward ring permutation
  int S = x ^ (x >> 1); S ^= S >> 2; S ^= S >> 4; S ^= S >> 8;
  return (S & 0xFF) | ((((x >> 8) ^ S) & 1) << 8);
}
__device__ __forceinline__ int physmap(int x){ return x ^ ((x >> 4) & 15); }

// UNIF=true: coeffs are wave-uniform (SGPR, scalar-cache loads) — sim path.
// UNIF=false: coeffs come from LDS (VGPR) — prep phase-2 path (avoids the
// same-kernel vector-store -> s_load scalar-cache visibility hazard).
template<int STRIDE, bool UNIF>
__device__ __forceinline__ void apply_rot(float2 amp[8], const float* rp){
  const float2 R0 = ((const float2*)rp)[0];            // (c, -s)
  const float2 R1 = ((const float2*)rp)[1];            // (s,  c)
  #pragma unroll
  for (int b = 0; b < 8; ++b){
    if (b & STRIDE) continue;
    const float2 u = amp[b], v = amp[b + STRIDE];
    if constexpr (UNIF){
      amp[b]          = pk_fma_s_lo(R0, u, pk_mul_s_hi(R0, v));   // c*u - s*v
      amp[b + STRIDE] = pk_fma_s_lo(R1, u, pk_mul_s_hi(R1, v));   // s*u + c*v
    } else {
      amp[b]          = pk_fma_vv_lo(R0, u, pk_mul_vv_hi(R0, v));
      amp[b + STRIDE] = pk_fma_vv_lo(R1, u, pk_mul_vv_hi(R1, v));
    }
  }
}

// One full layer: 3 rounds of rotations + deferred diagonal phase + ring-perm
// write. S is the wave-private state array; lb the layer's coefficient block.
template<bool UNIF>
__device__ __forceinline__ void run_layer(float2* __restrict__ S,
    const float* __restrict__ lb, const int lane,
    const int base1, const int base2, const int base3, const int baseF,
    const float2 NEG1P1){
  float2 amp[8];
  // round 1: wires 6,7,8 (x bits 2..0) — linear read (ring already folded)
  #pragma unroll
  for (int j = 0; j < 8; ++j) amp[j] = S[base1 ^ j];
  apply_rot<4, UNIF>(amp, lb + 6*4);
  apply_rot<2, UNIF>(amp, lb + 7*4);
  apply_rot<1, UNIF>(amp, lb + 8*4);
  #pragma unroll
  for (int j = 0; j < 8; ++j) S[base1 ^ j] = amp[j];
  // round 2: wires 3,4,5 (x bits 5..3)
  #pragma unroll
  for (int j = 0; j < 8; ++j) amp[j] = S[base2 ^ ((j << 3) ^ (j >> 1))];
  apply_rot<4, UNIF>(amp, lb + 3*4);
  apply_rot<2, UNIF>(amp, lb + 4*4);
  apply_rot<1, UNIF>(amp, lb + 5*4);
  #pragma unroll
  for (int j = 0; j < 8; ++j) S[base2 ^ ((j << 3) ^ (j >> 1))] = amp[j];
  // round 3: wires 0,1,2 (x bits 8..6)
  #pragma unroll
  for (int j = 0; j < 8; ++j) amp[j] = S[base3 ^ ((j << 6) ^ ((4*j) & 15))];
  apply_rot<4, UNIF>(amp, lb + 0*4);
  apply_rot<2, UNIF>(amp, lb + 1*4);
  apply_rot<1, UNIF>(amp, lb + 2*4);
  // deferred diagonal phase, split: amp = (amp*A[lane]) * B[j]
  {
    const float2 A  = *(const float2*)(lb + 128 + lane*2);
    const float2 A2 = pk_swapneg(A, NEG1P1);             // (-Ai, Ar)
    #pragma unroll
    for (int j = 0; j < 8; ++j)
      amp[j] = pk_fma_vv_lo(amp[j], A, pk_mul_vv_hi(amp[j], A2));
    #pragma unroll
    for (int j = 0; j < 8; ++j){
      const float2 P = *(const float2*)(lb + 64 + j*4);
      const float2 Q = *(const float2*)(lb + 64 + j*4 + 2);
      if constexpr (UNIF)
        amp[j] = pk_fma_vs_lo(amp[j], P, pk_mul_vs_hi(amp[j], Q));
      else
        amp[j] = pk_fma_vv_lo(amp[j], P, pk_mul_vv_hi(amp[j], Q));
    }
  }
  // write with this layer's ring folded: x = 64j + lane -> phys(F(x))
  #pragma unroll
  for (int j = 0; j < 8; ++j) S[baseF ^ physmap(Fperm(j << 6))] = amp[j];
}

// ---------------- kernel 1: MLP + tables + u0/Uv column sims ----------------
__global__ __launch_bounds__(576)
void prep_kernel(const float* __restrict__ t,  const float* __restrict__ w1,
                 const float* __restrict__ b1, const float* __restrict__ w2,
                 const float* __restrict__ b2, float* __restrict__ prep){
  __shared__ float sh[512];
  __shared__ float part[8][72];
  __shared__ float spar[72];
  __shared__ float tl[4][256];               // LDS copy of split tables
  __shared__ float ssc[3];                   // LDS copy of expm scalars
  __shared__ __align__(16) float2 vst[2][512];
  const int s = blockIdx.x;
  const float ts = t[s];
  for (int k = threadIdx.x; k < 512; k += 576){
    const float z = fmaf(ts, w1[k], b1[k]);
    sh[k] = z / (1.f + expf(-z));            // silu
  }
  __syncthreads();
  {
    const int p = threadIdx.x % 72, c = threadIdx.x / 72;   // c in 0..7
    float acc = 0.f;
    const int k0 = c*64;
    for (int k = k0; k < k0 + 64; ++k) acc = fmaf(sh[k], w2[k*72 + p], acc);
    part[c][p] = acc;
  }
  __syncthreads();
  if (threadIdx.x < 72){
    const int p = threadIdx.x;
    float acc = b2[p];
    #pragma unroll
    for (int c = 0; c < 8; ++c) acc += part[c][p];
    spar[p] = acc;
  }
  __syncthreads();
  float* pb = prep + (size_t)s*PSTRIDE;
  const int tid = threadIdx.x;
  if (tid < 256){                            // A[64] for layers 0..3
    const int l = tid >> 6, m = tid & 63;
    float2 acc = make_float2(1.f, 0.f);
    #pragma unroll
    for (int w = 3; w < 9; ++w){
      const float thz = spar[2*(9*l + w) + 1];
      float zi, zr; sincosf(0.5f*thz, &zi, &zr);
      const int bit = (m >> (8 - w)) & 1;
      acc = cmul(acc, make_float2(zr, bit ? zi : -zi));
    }
    pb[L_OFF(l) + 128 + 2*m]     = acc.x;
    pb[L_OFF(l) + 128 + 2*m + 1] = acc.y;
    tl[l][128 + 2*m]     = acc.x;
    tl[l][128 + 2*m + 1] = acc.y;
  } else if (tid < 288){                     // B[8] per layer (P,Q dual form)
    const int q = tid - 256, l = q >> 3, j = q & 7;
    float2 acc = make_float2(1.f, 0.f);
    #pragma unroll
    for (int w = 0; w < 3; ++w){
      const float thz = spar[2*(9*l + w) + 1];
      float zi, zr; sincosf(0.5f*thz, &zi, &zr);
      const int bit = (j >> (2 - w)) & 1;
      acc = cmul(acc, make_float2(zr, bit ? zi : -zi));
    }
    float* o = pb + L_OFF(l) + 64 + j*4;
    o[0] = acc.x; o[1] = acc.y; o[2] = -acc.y; o[3] = acc.x;
    float* o2 = &tl[l][64 + j*4];
    o2[0] = acc.x; o2[1] = acc.y; o2[2] = -acc.y; o2[3] = acc.x;
  } else if (tid < 324){                     // rot coeffs layers 0..3
    const int q = tid - 288, l = q / 9, w = q - l*9;
    const float thy = spar[2*(9*l + w)];
    float sy, cy; sincosf(0.5f*thy, &sy, &cy);
    float* o = pb + L_OFF(l) + w*4;
    o[0] = cy; o[1] = -sy; o[2] = sy; o[3] = cy;
    float* o2 = &tl[l][w*4];
    o2[0] = cy; o2[1] = -sy; o2[2] = sy; o2[3] = cy;
  } else if (tid < 333){                     // layer-1 dual gates
    const int w = tid - 324;
    const float thy = spar[2*w], thz = spar[2*w + 1];
    float sy, cy, zi, zr;
    sincosf(0.5f*thy, &sy, &cy);
    sincosf(0.5f*thz, &zi, &zr);             // e = (zr, zi)
    const float gr[4] = { zr*cy, -zr*sy, zr*sy, zr*cy };
    const float gi[4] = { -zi*cy, zi*sy, zi*sy, zi*cy };
    float* o = pb + GD_OFF + w*16;
    #pragma unroll
    for (int e = 0; e < 4; ++e){
      o[e*4+0] = gr[e]; o[e*4+1] = gi[e]; o[e*4+2] = -gi[e]; o[e*4+3] = gr[e];
    }
  } else if (tid < 405){                     // v[72]
    const int j = tid - 333;
    pb[V_OFF + j] = (j == 0) ? 0.f : 0.01f*spar[j];
  } else if (tid == 405){                    // expm scalars
    float th2 = 0.f;
    for (int j = 1; j < 72; ++j){ const float v = 0.01f*spar[j]; th2 = fmaf(v, v, th2); }
    const float th = sqrtf(th2);
    float alpha, beta;
    if (th > 1e-6f){
      alpha = sinf(th)/th;
      const float s2 = sinf(0.5f*th);
      beta = 2.f*s2*s2/th2;                  // (1-cos)/th^2, stable
    } else { alpha = 1.f - th2/6.f; beta = 0.5f; }
    pb[SC_OFF+0] = cosf(th);
    pb[SC_OFF+1] = alpha;
    pb[SC_OFF+2] = beta;
    ssc[0] = cosf(th); ssc[1] = alpha; ssc[2] = beta;
  }
  __syncthreads();
  // ---- phase 2: simulate circuit on e0 (wave 0) and on v (wave 1) ----
  if (tid < 128){
    const int wv = tid >> 6, lane = tid & 63;
    float2* const S = vst[wv];
    const float2 NEG1P1 = make_float2(-1.f, 1.f);
    const int base1 = (lane << 3) ^ ((lane >> 1) & 15);
    const int hq = lane >> 3, lq = lane & 7;
    const int base2 = (hq << 6) ^ ((hq << 2) & 15) ^ lq;
    const int base3 = lane ^ (lane >> 4);
    const int baseF = physmap(Fperm(lane));
    #pragma unroll
    for (int j = 0; j < 8; ++j){
      const int x = (lane << 3) + j;
      float re;
      if (wv == 0) re = (x == 0) ? 1.f : 0.f;
      else         re = (x >= 1 && x < 72) ? 0.01f*spar[x] : 0.f;
      S[base1 ^ j] = make_float2(re, 0.f);
    }
    #pragma unroll
    for (int L = 0; L < 4; ++L)
      run_layer<false>(S, &tl[L][0], lane, base1, base2, base3, baseF, NEG1P1);
  }
  __syncthreads();
  if (tid < 512){                            // w / c0 tables
    const int a  = tid;
    const int pa = a ^ ((a >> 4) & 15);
    const float u0 = vst[0][pa].x;
    const float uv = vst[1][pa].x;
    pb[W_OFF  + a] = fmaf(ssc[1], u0, -ssc[2]*uv);   // alpha*u0 - beta*Uv
    pb[C0_OFF + a] = fmaf(ssc[0], u0, -ssc[1]*uv);   // cth*u0 - alpha*Uv
  }
}

// ---------------- kernel 2: circuit sim -> out = U*expm (fused) ----------------
// Grid: blockIdx = cb*64 + s. Block 512 thr = 8 waves, one wave per column,
// st[wid] wave-private -> no barriers in the layer loop. Rotation coeffs /
// B-phases are wave-uniform (SGPR); A-phase is a per-lane float2 load.
// __launch_bounds__(512,6): 85-VGPR budget (was 64 -> 32-VGPR starved body);
// occupancy stays LDS-capped at ~22 waves/CU (measured ~90KB/CU effective).
__global__ __launch_bounds__(512, 6)
void sim_kernel(const float* __restrict__ prep, float* __restrict__ out){
  __shared__ __align__(16) float2 st[8][512];
  const int s    = blockIdx.x & 63;
  const int cb   = blockIdx.x >> 6;
  const int wid  = threadIdx.x >> 6;
  const int lane = threadIdx.x & 63;
  const int col  = cb*8 + wid;               // input basis state / U column
  const float* gp = prep + (size_t)s*PSTRIDE;
  float2* const S = st[wid];
  const float2 NEG1P1 = make_float2(-1.f, 1.f);

  float2 amp[8];
  // ---- layer 1 on basis state |col>: product state, dual-form gates ----
  {
    float2 base = make_float2(1.f, 0.f);
    #pragma unroll
    for (int w = 0; w < 6; ++w){
      const int xb = (lane >> (5 - w)) & 1;  // x bit 8-w  (lane = x>>3)
      const int ib = (col  >> (8 - w)) & 1;  // input bit of wire w
      const float4 gd = *(const float4*)(gp + GD_OFF + w*16 + (xb*2 + ib)*4);
      const float2 d1 = make_float2(gd.x, gd.y);
      const float2 d2 = make_float2(gd.z, gd.w);
      base = pk_fma_vv_lo(base, d1, pk_mul_vv_hi(base, d2));   // base *= g
    }
    const int i6 = (col >> 2) & 1, i7 = (col >> 1) & 1, i8 = col & 1;
    float2 g6[2]; float4 g7d[2], g8d[2];
    #pragma unroll
    for (int r = 0; r < 2; ++r){
      g6[r]  = *(const float2*)(gp + GD_OFF + 6*16 + (r*2 + i6)*4);
      g7d[r] = *(const float4*)(gp + GD_OFF + 7*16 + (r*2 + i7)*4);
      g8d[r] = *(const float4*)(gp + GD_OFF + 8*16 + (r*2 + i8)*4);
    }
    float2 g67[4];
    #pragma unroll
    for (int a = 0; a < 2; ++a){
      #pragma unroll
      for (int b = 0; b < 2; ++b){
        const float2 d1 = make_float2(g7d[b].x, g7d[b].y);
        const float2 d2 = make_float2(g7d[b].z, g7d[b].w);
        g67[a*2+b] = pk_fma_vv_lo(g6[a], d1, pk_mul_vv_hi(g6[a], d2));
      }
    }
    const float2 bd2 = pk_swapneg(base, NEG1P1);
    #pragma unroll
    for (int j = 0; j < 8; ++j){
      const float4 g8 = g8d[j & 1];
      const float2 e1 = make_float2(g8.x, g8.y);
      const float2 e2 = make_float2(g8.z, g8.w);
      const float2 T  = pk_fma_vv_lo(g67[j >> 1], e1, pk_mul_vv_hi(g67[j >> 1], e2));
      amp[j] = pk_fma_vv_lo(T, base, pk_mul_vv_hi(T, bd2));    // T * base
    }
    // write with ring-1 folded: element x = 8*lane + j -> slot phys(F(x))
    const int bFI = physmap(Fperm(lane << 3));
    #pragma unroll
    for (int j = 0; j < 8; ++j) S[bFI ^ physmap(Fperm(j))] = amp[j];
  }

  const int base1 = (lane << 3) ^ ((lane >> 1) & 15);            // phys(8*lane)
  const int hq = lane >> 3, lq = lane & 7;
  const int base2 = (hq << 6) ^ ((hq << 2) & 15) ^ lq;           // phys(64h)^l
  const int base3 = lane ^ (lane >> 4);                          // phys(lane)
  const int baseF = physmap(Fperm(lane));

  run_layer<true>(S, gp + L_OFF(1), lane, base1, base2, base3, baseF, NEG1P1);
  run_layer<true>(S, gp + L_OFF(2), lane, base1, base2, base3, baseF, NEG1P1);
  run_layer<true>(S, gp + L_OFF(3), lane, base1, base2, base3, baseF, NEG1P1);

  __syncthreads();                            // output reads other waves' arrays
  // transposed write of Re(state) with fused rank-2 expm correction.
  const float* wt  = gp + W_OFF;
  const float* c0t = gp + C0_OFF;
  const float* vt  = gp + V_OFF;
  #pragma unroll
  for (int rep = 0; rep < 2; ++rep){
    const int a  = (threadIdx.x >> 1) + rep*256;
    const int q  = threadIdx.x & 1;
    const int pa = a ^ ((a >> 4) & 15);
    float4 vv;
    vv.x = st[q*4 + 0][pa].x;
    vv.y = st[q*4 + 1][pa].x;
    vv.z = st[q*4 + 2][pa].x;
    vv.w = st[q*4 + 3][pa].x;
    if (cb < 9){                              // cols 0..71 get the correction
      const float  wa = wt[a];
      const float4 vj = *(const float4*)(vt + cb*8 + q*4);
      vv.x = fmaf(wa, vj.x, vv.x);
      vv.y = fmaf(wa, vj.y, vv.y);
      vv.z = fmaf(wa, vj.z, vv.z);
      vv.w = fmaf(wa, vj.w, vv.w);
      if ((cb | q) == 0) vv.x = c0t[a];       // column 0 closed form
    }
    *(float4*)&out[(size_t)s*262144 + (size_t)a*512 + cb*8 + q*4] = vv;
  }
}

extern "C" void kernel_launch(void* const* d_in, const int* in_sizes, int n_in,
                              void* d_out, int out_size, void* d_ws, size_t ws_size,
                              hipStream_t stream){
  const float* t  = (const float*)d_in[0];
  const float* w1 = (const float*)d_in[1];
  const float* b1 = (const float*)d_in[2];
  const float* w2 = (const float*)d_in[3];
  const float* b2 = (const float*)d_in[4];
  float* out  = (float*)d_out;
  float* prep = (float*)d_ws;                 // 64*2560 floats = 640 KiB used
  prep_kernel<<<64,   576, 0, stream>>>(t, w1, b1, w2, b2, prep);
  sim_kernel <<<4096, 512, 0, stream>>>(prep, out);
}

// Round 7
// 143.185 us; speedup vs baseline: 1.1222x; 1.0070x over previous
//
#include <hip/hip_runtime.h>
#include <math.h>

// TQUnitaryBuilder: 9-wire, 4-layer circuit -> U (512x512 real) per sample,
// fused with closed-form expm of the rank-2 skew matrix and the final matmul.
//
// Round-7: hybrid exchange layer. In the round-1 register layout amp[j] of
// lane L holds element x = 8L + j (slot phys(x) = base1 ^ j). Wires 3,4,5
// live on LANE bits 2,1,0 -> their butterflies are value-exchanges with
// labels unchanged: wire 3 via ds_swizzle 0x101F (lane^4, crossbar permute),
// wires 4,5 via DPP quad_perm (lane^2 = 0x4E, lane^1 = 0xB1, pure VALU).
// This deletes the whole R2 LDS round-trip (16 b64 + addressing + one
// ~100-cycle latency link per layer): DS cycles/layer 192->160, round-trips
// 3->2. Cross-rotation: new = c*own + (bit ? s : -s)*partner = 2 pk/el.
// R1/R3 rounds, diag phase, ring-fold write, epilogue, prep: verbatim.
//
// ws layout (floats), stride 2560 per sample s:
//   [0..143]    layer-1 dual gates: 9 x 4 entries x (gr,gi,-gi,gr)
//   [144..146]  expm scalars: cos(th), alpha=sin/th, beta=(1-cos)/th^2
//   [160+l*256 ..] split blocks for layers l=0..3:
//     +0..35    rot coeffs: 9 wires x {c,-s,s,c}
//     +64..95   B-phase:    8 j x {Br,Bi,-Bi,Br} (P,Q dual form)
//     +128..255 A-phase:    64 m x {Ar,Ai}
//   [1184..1255] v[72] (0.01*params, v[0]=0)
//   [1280..1791] w[512]   = alpha*u0 - beta*Uv
//   [1792..2303] c0[512]  = cos(th)*u0 - alpha*Uv
// Total: 64 * 2560 * 4 B = 640 KiB of d_ws.

#define PSTRIDE 2560
#define GD_OFF  0
#define SC_OFF  144
#define L_OFF(l) (160 + (l)*256)
#define V_OFF   1184
#define W_OFF   1280
#define C0_OFF  1792

__device__ __forceinline__ float2 cmul(float2 a, float2 b){
  return make_float2(fmaf(a.x, b.x, -a.y*b.y), fmaf(a.x, b.y, a.y*b.x));
}

// ---- packed fp32 helpers (v_pk_fma_f32 / v_pk_mul_f32, full-rate) ----
__device__ __forceinline__ float2 pk_fma_s_lo(float2 s2, float2 b, float2 c){
  float2 d;  // d = s2.x * b + c   (s2 SGPR)
  asm("v_pk_fma_f32 %0, %1, %2, %3 op_sel:[0,0,0] op_sel_hi:[0,1,1]"
      : "=v"(d) : "s"(s2), "v"(b), "v"(c));
  return d;
}
__device__ __forceinline__ float2 pk_mul_s_hi(float2 s2, float2 b){
  float2 d;  // d = s2.y * b
  asm("v_pk_mul_f32 %0, %1, %2 op_sel:[1,0] op_sel_hi:[1,1]"
      : "=v"(d) : "s"(s2), "v"(b));
  return d;
}
__device__ __forceinline__ float2 pk_mul_s_lo(float2 s2, float2 b){
  float2 d;  // d = s2.x * b
  asm("v_pk_mul_f32 %0, %1, %2 op_sel:[0,0] op_sel_hi:[0,1]"
      : "=v"(d) : "s"(s2), "v"(b));
  return d;
}
__device__ __forceinline__ float2 pk_fma_vs_lo(float2 a, float2 b, float2 c){
  float2 d;  // d = a.x * b + c   (a VGPR broadcast, b SGPR)
  asm("v_pk_fma_f32 %0, %1, %2, %3 op_sel:[0,0,0] op_sel_hi:[0,1,1]"
      : "=v"(d) : "v"(a), "s"(b), "v"(c));
  return d;
}
__device__ __forceinline__ float2 pk_mul_vs_hi(float2 a, float2 b){
  float2 d;  // d = a.y * b
  asm("v_pk_mul_f32 %0, %1, %2 op_sel:[1,0] op_sel_hi:[1,1]"
      : "=v"(d) : "v"(a), "s"(b));
  return d;
}
__device__ __forceinline__ float2 pk_fma_vv_lo(float2 a, float2 b, float2 c){
  float2 d;  // d = a.x * b + c
  asm("v_pk_fma_f32 %0, %1, %2, %3 op_sel:[0,0,0] op_sel_hi:[0,1,1]"
      : "=v"(d) : "v"(a), "v"(b), "v"(c));
  return d;
}
__device__ __forceinline__ float2 pk_mul_vv_hi(float2 a, float2 b){
  float2 d;  // d = a.y * b
  asm("v_pk_mul_f32 %0, %1, %2 op_sel:[1,0] op_sel_hi:[1,1]"
      : "=v"(d) : "v"(a), "v"(b));
  return d;
}
__device__ __forceinline__ float2 pk_swapneg(float2 c, float2 n){
  float2 d;  // d = (-c.y, c.x)   with n = (-1, 1)
  asm("v_pk_mul_f32 %0, %1, %2 op_sel:[1,0] op_sel_hi:[0,1]"
      : "=v"(d) : "v"(c), "v"(n));
  return d;
}

// ---- cross-lane partner fetch (value exchange, labels unchanged) ----
template<int OFS>                            // ds_swizzle BitMode xor pattern
__device__ __forceinline__ float2 swz2(float2 v){
  const int x = __builtin_amdgcn_ds_swizzle(__float_as_int(v.x), OFS);
  const int y = __builtin_amdgcn_ds_swizzle(__float_as_int(v.y), OFS);
  return make_float2(__int_as_float(x), __int_as_float(y));
}
template<int CTRL>                           // DPP quad_perm
__device__ __forceinline__ float2 dpp2(float2 v){
  const int x = __builtin_amdgcn_mov_dpp(__float_as_int(v.x), CTRL, 0xF, 0xF, true);
  const int y = __builtin_amdgcn_mov_dpp(__float_as_int(v.y), CTRL, 0xF, 0xF, true);
  return make_float2(__int_as_float(x), __int_as_float(y));
}

__device__ __forceinline__ int Fperm(int x){       // forward ring permutation
  int S = x ^ (x >> 1); S ^= S >> 2; S ^= S >> 4; S ^= S >> 8;
  return (S & 0xFF) | ((((x >> 8) ^ S) & 1) << 8);
}
__device__ __forceinline__ int physmap(int x){ return x ^ ((x >> 4) & 15); }

// UNIF=true: coeffs are wave-uniform (SGPR, scalar-cache loads) — sim path.
// UNIF=false: coeffs come from LDS (VGPR) — prep phase-2 path.
template<int STRIDE, bool UNIF>
__device__ __forceinline__ void apply_rot(float2 amp[8], const float* rp){
  const float2 R0 = ((const float2*)rp)[0];            // (c, -s)
  const float2 R1 = ((const float2*)rp)[1];            // (s,  c)
  #pragma unroll
  for (int b = 0; b < 8; ++b){
    if (b & STRIDE) continue;
    const float2 u = amp[b], v = amp[b + STRIDE];
    if constexpr (UNIF){
      amp[b]          = pk_fma_s_lo(R0, u, pk_mul_s_hi(R0, v));   // c*u - s*v
      amp[b + STRIDE] = pk_fma_s_lo(R1, u, pk_mul_s_hi(R1, v));   // s*u + c*v
    } else {
      amp[b]          = pk_fma_vv_lo(R0, u, pk_mul_vv_hi(R0, v));
      amp[b + STRIDE] = pk_fma_vv_lo(R1, u, pk_mul_vv_hi(R1, v));
    }
  }
}

// ---------------- OLD 3-round layer (prep phase-2 only, verbatim) ----------
__device__ __forceinline__ void run_layer2(float2* __restrict__ S,
    const float* __restrict__ lb, const int lane,
    const int base1, const int base2, const int base3, const int baseF,
    const float2 NEG1P1){
  float2 amp[8];
  #pragma unroll
  for (int j = 0; j < 8; ++j) amp[j] = S[base1 ^ j];
  apply_rot<4,false>(amp, lb + 6*4);
  apply_rot<2,false>(amp, lb + 7*4);
  apply_rot<1,false>(amp, lb + 8*4);
  #pragma unroll
  for (int j = 0; j < 8; ++j) S[base1 ^ j] = amp[j];
  #pragma unroll
  for (int j = 0; j < 8; ++j) amp[j] = S[base2 ^ ((j << 3) ^ (j >> 1))];
  apply_rot<4,false>(amp, lb + 3*4);
  apply_rot<2,false>(amp, lb + 4*4);
  apply_rot<1,false>(amp, lb + 5*4);
  #pragma unroll
  for (int j = 0; j < 8; ++j) S[base2 ^ ((j << 3) ^ (j >> 1))] = amp[j];
  #pragma unroll
  for (int j = 0; j < 8; ++j) amp[j] = S[base3 ^ ((j << 6) ^ ((4*j) & 15))];
  apply_rot<4,false>(amp, lb + 0*4);
  apply_rot<2,false>(amp, lb + 1*4);
  apply_rot<1,false>(amp, lb + 2*4);
  {
    const float2 A  = *(const float2*)(lb + 128 + lane*2);
    const float2 A2 = pk_swapneg(A, NEG1P1);             // (-Ai, Ar)
    #pragma unroll
    for (int j = 0; j < 8; ++j)
      amp[j] = pk_fma_vv_lo(amp[j], A, pk_mul_vv_hi(amp[j], A2));
    #pragma unroll
    for (int j = 0; j < 8; ++j){
      const float2 P = *(const float2*)(lb + 64 + j*4);
      const float2 Q = *(const float2*)(lb + 64 + j*4 + 2);
      amp[j] = pk_fma_vv_lo(amp[j], P, pk_mul_vv_hi(amp[j], Q));
    }
  }
  #pragma unroll
  for (int j = 0; j < 8; ++j) S[baseF ^ physmap(Fperm(j << 6))] = amp[j];
}

// ---------------- NEW hybrid layer (sim path, SGPR coeffs) -----------------
// Cross rotation on a lane-bit wire: new = c*own + (bit? s : -s)*partner.
// GET fetches the partner value (swizzle/DPP); labels never move.
#define XROT(GET, RP, BIT) {                                        \
    const float2 R0 = ((const float2*)(RP))[0];   /* (c,-s) SGPR */ \
    const float2 R1 = ((const float2*)(RP))[1];   /* (s, c) SGPR */ \
    const float  Bs = (BIT) ? R1.x : R0.y;                          \
    const float2 Bv = make_float2(Bs, Bs);                          \
    _Pragma("unroll")                                               \
    for (int j = 0; j < 8; ++j){                                    \
      const float2 p = GET(amp[j]);                                 \
      amp[j] = pk_fma_vv_lo(Bv, p, pk_mul_s_lo(R0, amp[j]));        \
    }                                                               \
  }

__device__ __forceinline__ void run_layer_h(float2* __restrict__ S,
    const float* __restrict__ lb, const int lane,
    const int base1, const int base3, const int baseF,
    const float2 NEG1P1){
  float2 amp[8];
  // R1: linear read (ring already folded); amp[j] = element 8*lane + j
  #pragma unroll
  for (int j = 0; j < 8; ++j) amp[j] = S[base1 ^ j];
  // wires 6,7,8: local j bits 2,1,0
  apply_rot<4,true>(amp, lb + 6*4);
  apply_rot<2,true>(amp, lb + 7*4);
  apply_rot<1,true>(amp, lb + 8*4);
  // wires 3,4,5: x bits 5,4,3 = lane bits 2,1,0 — value exchanges
  XROT(swz2<0x101F>, lb + 3*4, (lane >> 2) & 1);   // lane^4 via ds_swizzle
  XROT(dpp2<0x4E>,   lb + 4*4, (lane >> 1) & 1);   // lane^2 via DPP [2,3,0,1]
  XROT(dpp2<0xB1>,   lb + 5*4, lane & 1);          // lane^1 via DPP [1,0,3,2]
  // write back, re-read in R3 pattern (x = 64j + lane)
  #pragma unroll
  for (int j = 0; j < 8; ++j) S[base1 ^ j] = amp[j];
  #pragma unroll
  for (int j = 0; j < 8; ++j) amp[j] = S[base3 ^ ((j << 6) ^ ((4*j) & 15))];
  // wires 0,1,2: local j bits (x bits 8,7,6)
  apply_rot<4,true>(amp, lb + 0*4);
  apply_rot<2,true>(amp, lb + 1*4);
  apply_rot<1,true>(amp, lb + 2*4);
  // deferred diagonal phase, split: amp = (amp*A[lane]) * B[j]
  {
    const float2 A  = *(const float2*)(lb + 128 + lane*2);
    const float2 A2 = pk_swapneg(A, NEG1P1);             // (-Ai, Ar)
    #pragma unroll
    for (int j = 0; j < 8; ++j)
      amp[j] = pk_fma_vv_lo(amp[j], A, pk_mul_vv_hi(amp[j], A2));
    #pragma unroll
    for (int j = 0; j < 8; ++j){
      const float2 P = *(const float2*)(lb + 64 + j*4);
      const float2 Q = *(const float2*)(lb + 64 + j*4 + 2);
      amp[j] = pk_fma_vs_lo(amp[j], P, pk_mul_vs_hi(amp[j], Q));
    }
  }
  // write with this layer's ring folded: x = 64j + lane -> phys(F(x))
  #pragma unroll
  for (int j = 0; j < 8; ++j) S[baseF ^ physmap(Fperm(j << 6))] = amp[j];
}

// ---------------- kernel 1: MLP + tables + u0/Uv column sims ----------------
__global__ __launch_bounds__(576)
void prep_kernel(const float* __restrict__ t,  const float* __restrict__ w1,
                 const float* __restrict__ b1, const float* __restrict__ w2,
                 const float* __restrict__ b2, float* __restrict__ prep){
  __shared__ float sh[512];
  __shared__ float part[8][72];
  __shared__ float spar[72];
  __shared__ float tl[4][256];               // LDS copy of split tables
  __shared__ float ssc[3];                   // LDS copy of expm scalars
  __shared__ __align__(16) float2 vst[2][512];
  const int s = blockIdx.x;
  const float ts = t[s];
  for (int k = threadIdx.x; k < 512; k += 576){
    const float z = fmaf(ts, w1[k], b1[k]);
    sh[k] = z / (1.f + expf(-z));            // silu
  }
  __syncthreads();
  {
    const int p = threadIdx.x % 72, c = threadIdx.x / 72;   // c in 0..7
    float acc = 0.f;
    const int k0 = c*64;
    for (int k = k0; k < k0 + 64; ++k) acc = fmaf(sh[k], w2[k*72 + p], acc);
    part[c][p] = acc;
  }
  __syncthreads();
  if (threadIdx.x < 72){
    const int p = threadIdx.x;
    float acc = b2[p];
    #pragma unroll
    for (int c = 0; c < 8; ++c) acc += part[c][p];
    spar[p] = acc;
  }
  __syncthreads();
  float* pb = prep + (size_t)s*PSTRIDE;
  const int tid = threadIdx.x;
  if (tid < 256){                            // A[64] for layers 0..3
    const int l = tid >> 6, m = tid & 63;
    float2 acc = make_float2(1.f, 0.f);
    #pragma unroll
    for (int w = 3; w < 9; ++w){
      const float thz = spar[2*(9*l + w) + 1];
      float zi, zr; sincosf(0.5f*thz, &zi, &zr);
      const int bit = (m >> (8 - w)) & 1;
      acc = cmul(acc, make_float2(zr, bit ? zi : -zi));
    }
    pb[L_OFF(l) + 128 + 2*m]     = acc.x;
    pb[L_OFF(l) + 128 + 2*m + 1] = acc.y;
    tl[l][128 + 2*m]     = acc.x;
    tl[l][128 + 2*m + 1] = acc.y;
  } else if (tid < 288){                     // B[8] per layer (P,Q dual form)
    const int q = tid - 256, l = q >> 3, j = q & 7;
    float2 acc = make_float2(1.f, 0.f);
    #pragma unroll
    for (int w = 0; w < 3; ++w){
      const float thz = spar[2*(9*l + w) + 1];
      float zi, zr; sincosf(0.5f*thz, &zi, &zr);
      const int bit = (j >> (2 - w)) & 1;
      acc = cmul(acc, make_float2(zr, bit ? zi : -zi));
    }
    float* o = pb + L_OFF(l) + 64 + j*4;
    o[0] = acc.x; o[1] = acc.y; o[2] = -acc.y; o[3] = acc.x;
    float* o2 = &tl[l][64 + j*4];
    o2[0] = acc.x; o2[1] = acc.y; o2[2] = -acc.y; o2[3] = acc.x;
  } else if (tid < 324){                     // rot coeffs layers 0..3
    const int q = tid - 288, l = q / 9, w = q - l*9;
    const float thy = spar[2*(9*l + w)];
    float sy, cy; sincosf(0.5f*thy, &sy, &cy);
    float* o = pb + L_OFF(l) + w*4;
    o[0] = cy; o[1] = -sy; o[2] = sy; o[3] = cy;
    float* o2 = &tl[l][w*4];
    o2[0] = cy; o2[1] = -sy; o2[2] = sy; o2[3] = cy;
  } else if (tid < 333){                     // layer-1 dual gates
    const int w = tid - 324;
    const float thy = spar[2*w], thz = spar[2*w + 1];
    float sy, cy, zi, zr;
    sincosf(0.5f*thy, &sy, &cy);
    sincosf(0.5f*thz, &zi, &zr);             // e = (zr, zi)
    const float gr[4] = { zr*cy, -zr*sy, zr*sy, zr*cy };
    const float gi[4] = { -zi*cy, zi*sy, zi*sy, zi*cy };
    float* o = pb + GD_OFF + w*16;
    #pragma unroll
    for (int e = 0; e < 4; ++e){
      o[e*4+0] = gr[e]; o[e*4+1] = gi[e]; o[e*4+2] = -gi[e]; o[e*4+3] = gr[e];
    }
  } else if (tid < 405){                     // v[72]
    const int j = tid - 333;
    pb[V_OFF + j] = (j == 0) ? 0.f : 0.01f*spar[j];
  } else if (tid == 405){                    // expm scalars
    float th2 = 0.f;
    for (int j = 1; j < 72; ++j){ const float v = 0.01f*spar[j]; th2 = fmaf(v, v, th2); }
    const float th = sqrtf(th2);
    float alpha, beta;
    if (th > 1e-6f){
      alpha = sinf(th)/th;
      const float s2 = sinf(0.5f*th);
      beta = 2.f*s2*s2/th2;                  // (1-cos)/th^2, stable
    } else { alpha = 1.f - th2/6.f; beta = 0.5f; }
    pb[SC_OFF+0] = cosf(th);
    pb[SC_OFF+1] = alpha;
    pb[SC_OFF+2] = beta;
    ssc[0] = cosf(th); ssc[1] = alpha; ssc[2] = beta;
  }
  __syncthreads();
  // ---- phase 2: simulate circuit on e0 (wave 0) and on v (wave 1) ----
  if (tid < 128){
    const int wv = tid >> 6, lane = tid & 63;
    float2* const S = vst[wv];
    const float2 NEG1P1 = make_float2(-1.f, 1.f);
    const int base1 = (lane << 3) ^ ((lane >> 1) & 15);
    const int hq = lane >> 3, lq = lane & 7;
    const int base2 = (hq << 6) ^ ((hq << 2) & 15) ^ lq;
    const int base3 = lane ^ (lane >> 4);
    const int baseF = physmap(Fperm(lane));
    #pragma unroll
    for (int j = 0; j < 8; ++j){
      const int x = (lane << 3) + j;
      float re;
      if (wv == 0) re = (x == 0) ? 1.f : 0.f;
      else         re = (x >= 1 && x < 72) ? 0.01f*spar[x] : 0.f;
      S[base1 ^ j] = make_float2(re, 0.f);
    }
    #pragma unroll
    for (int L = 0; L < 4; ++L)
      run_layer2(S, &tl[L][0], lane, base1, base2, base3, baseF, NEG1P1);
  }
  __syncthreads();
  if (tid < 512){                            // w / c0 tables
    const int a  = tid;
    const int pa = a ^ ((a >> 4) & 15);
    const float u0 = vst[0][pa].x;
    const float uv = vst[1][pa].x;
    pb[W_OFF  + a] = fmaf(ssc[1], u0, -ssc[2]*uv);   // alpha*u0 - beta*Uv
    pb[C0_OFF + a] = fmaf(ssc[0], u0, -ssc[1]*uv);   // cth*u0 - alpha*Uv
  }
}

// ---------------- kernel 2: circuit sim -> out = U*expm (fused) ----------------
// Grid: blockIdx = cb*64 + s. Block 512 thr = 8 waves, one wave per column,
// st[wid] wave-private -> no barriers in the layer loop.
__global__ __launch_bounds__(512, 6)
void sim_kernel(const float* __restrict__ prep, float* __restrict__ out){
  __shared__ __align__(16) float2 st[8][512];
  const int s    = blockIdx.x & 63;
  const int cb   = blockIdx.x >> 6;
  const int wid  = threadIdx.x >> 6;
  const int lane = threadIdx.x & 63;
  const int col  = cb*8 + wid;               // input basis state / U column
  const float* gp = prep + (size_t)s*PSTRIDE;
  float2* const S = st[wid];
  const float2 NEG1P1 = make_float2(-1.f, 1.f);

  float2 amp[8];
  // ---- layer 1 on basis state |col>: product state, dual-form gates ----
  {
    float2 base = make_float2(1.f, 0.f);
    #pragma unroll
    for (int w = 0; w < 6; ++w){
      const int xb = (lane >> (5 - w)) & 1;  // x bit 8-w  (lane = x>>3)
      const int ib = (col  >> (8 - w)) & 1;  // input bit of wire w
      const float4 gd = *(const float4*)(gp + GD_OFF + w*16 + (xb*2 + ib)*4);
      const float2 d1 = make_float2(gd.x, gd.y);
      const float2 d2 = make_float2(gd.z, gd.w);
      base = pk_fma_vv_lo(base, d1, pk_mul_vv_hi(base, d2));   // base *= g
    }
    const int i6 = (col >> 2) & 1, i7 = (col >> 1) & 1, i8 = col & 1;
    float2 g6[2]; float4 g7d[2], g8d[2];
    #pragma unroll
    for (int r = 0; r < 2; ++r){
      g6[r]  = *(const float2*)(gp + GD_OFF + 6*16 + (r*2 + i6)*4);
      g7d[r] = *(const float4*)(gp + GD_OFF + 7*16 + (r*2 + i7)*4);
      g8d[r] = *(const float4*)(gp + GD_OFF + 8*16 + (r*2 + i8)*4);
    }
    float2 g67[4];
    #pragma unroll
    for (int a = 0; a < 2; ++a){
      #pragma unroll
      for (int b = 0; b < 2; ++b){
        const float2 d1 = make_float2(g7d[b].x, g7d[b].y);
        const float2 d2 = make_float2(g7d[b].z, g7d[b].w);
        g67[a*2+b] = pk_fma_vv_lo(g6[a], d1, pk_mul_vv_hi(g6[a], d2));
      }
    }
    const float2 bd2 = pk_swapneg(base, NEG1P1);
    #pragma unroll
    for (int j = 0; j < 8; ++j){
      const float4 g8 = g8d[j & 1];
      const float2 e1 = make_float2(g8.x, g8.y);
      const float2 e2 = make_float2(g8.z, g8.w);
      const float2 T  = pk_fma_vv_lo(g67[j >> 1], e1, pk_mul_vv_hi(g67[j >> 1], e2));
      amp[j] = pk_fma_vv_lo(T, base, pk_mul_vv_hi(T, bd2));    // T * base
    }
    // write with ring-1 folded: element x = 8*lane + j -> slot phys(F(x))
    const int bFI = physmap(Fperm(lane << 3));
    #pragma unroll
    for (int j = 0; j < 8; ++j) S[bFI ^ physmap(Fperm(j))] = amp[j];
  }

  const int base1 = (lane << 3) ^ ((lane >> 1) & 15);            // phys(8*lane)
  const int base3 = lane ^ (lane >> 4);                          // phys(lane)
  const int baseF = physmap(Fperm(lane));

  run_layer_h(S, gp + L_OFF(1), lane, base1, base3, baseF, NEG1P1);
  run_layer_h(S, gp + L_OFF(2), lane, base1, base3, baseF, NEG1P1);
  run_layer_h(S, gp + L_OFF(3), lane, base1, base3, baseF, NEG1P1);

  __syncthreads();                            // output reads other waves' arrays
  // transposed write of Re(state) with fused rank-2 expm correction.
  const float* wt  = gp + W_OFF;
  const float* c0t = gp + C0_OFF;
  const float* vt  = gp + V_OFF;
  #pragma unroll
  for (int rep = 0; rep < 2; ++rep){
    const int a  = (threadIdx.x >> 1) + rep*256;
    const int q  = threadIdx.x & 1;
    const int pa = a ^ ((a >> 4) & 15);
    float4 vv;
    vv.x = st[q*4 + 0][pa].x;
    vv.y = st[q*4 + 1][pa].x;
    vv.z = st[q*4 + 2][pa].x;
    vv.w = st[q*4 + 3][pa].x;
    if (cb < 9){                              // cols 0..71 get the correction
      const float  wa = wt[a];
      const float4 vj = *(const float4*)(vt + cb*8 + q*4);
      vv.x = fmaf(wa, vj.x, vv.x);
      vv.y = fmaf(wa, vj.y, vv.y);
      vv.z = fmaf(wa, vj.z, vv.z);
      vv.w = fmaf(wa, vj.w, vv.w);
      if ((cb | q) == 0) vv.x = c0t[a];       // column 0 closed form
    }
    *(float4*)&out[(size_t)s*262144 + (size_t)a*512 + cb*8 + q*4] = vv;
  }
}

extern "C" void kernel_launch(void* const* d_in, const int* in_sizes, int n_in,
                              void* d_out, int out_size, void* d_ws, size_t ws_size,
                              hipStream_t stream){
  const float* t  = (const float*)d_in[0];
  const float* w1 = (const float*)d_in[1];
  const float* b1 = (const float*)d_in[2];
  const float* w2 = (const float*)d_in[3];
  const float* b2 = (const float*)d_in[4];
  float* out  = (float*)d_out;
  float* prep = (float*)d_ws;                 // 64*2560 floats = 640 KiB used
  prep_kernel<<<64,   576, 0, stream>>>(t, w1, b1, w2, b2, prep);
  sim_kernel <<<4096, 512, 0, stream>>>(prep, out);
}